// Round 6
// baseline (976.335 us; speedup 1.0000x reference)
//
#include <hip/hip_runtime.h>
#include <hip/hip_cooperative_groups.h>
#include <math.h>

namespace cg = cooperative_groups;

// ---------------------------------------------------------------------------
// Deep4Net via bf16 MFMA (fp32 accum). Two dispatch modes, SAME device code:
//  (a) single cooperative kernel k_all: phases {prep, conv12, conv3, conv4,
//      conv5, head} separated by grid.sync() -- kills the ~8-10us x6 launch
//      boundaries that dominated round-4's removable cost. Grid is sized at
//      runtime from hipOccupancyMaxActiveBlocksPerMultiprocessor (round-5's
//      silent failure was an unchecked hard-coded 1024-block coop launch).
//  (b) fallback multi-kernel path (verified 148.7us round-4 structure) if the
//      cooperative launch is rejected -- return code checked this time.
//
// conv1+conv2 fused algebraically; pool(elu)=elu(pool).
//   out[o][t] += sum_i wk[k][o][i] * xT[t+k][i]
// Weights FRAGMENT-ORDERED by prep: for each (k, ib, otile) a 512-short
// block where lane l holds shorts [l*8..+7] = its exact MFMA A-fragment ->
// wave A-load = one coalesced 1KB global_load_dwordx4.
// B-frag: xT[t][i: quad*8..+7] staged in LDS (rows padded +4 shorts).
// Epilogue scratch sc transposed [col][o], odd stride MSPAN+1.
//
// Workspace: float region then short(bf16) region.
#define F_BC   0         // 32   combined bias (padded)
#define F_B2   32        // 64
#define F_B3   96        // 128
#define F_B4   224       // 224
#define F_P4   448       // 256*1400 f32 features
#define SHORT_BASE 717696  // short index of bf16 region
#define WK12   0         // [10][1][2][512]   (k, ib, otile, frag)
#define WK3    10240     // [10][1][4][512]
#define WK4    30720     // [10][2][8][512]
#define WK5    112640    // [10][4][14][512]
#define P1T    399360    // [256][330][32]
#define P2T    3102720   // [256][107][64]
#define P3T    4855808   // [256][32][128]

#define SMEM_BYTES 20240 // max phase usage (conv12 and conv4 both hit 20240)
// ---------------------------------------------------------------------------

typedef __attribute__((ext_vector_type(8))) short short8;
typedef __attribute__((ext_vector_type(4))) float f32x4;

__device__ __forceinline__ short f2bf(float f) {
    union { float f; unsigned u; } v; v.f = f;
    unsigned r = v.u + 0x7FFF + ((v.u >> 16) & 1);
    return (short)(r >> 16);
}

// ---- prep virtual block (vb 0 = biases; vb 1..1560 = weights) -------------
__device__ __forceinline__ void prep_vb(
    int vb, unsigned char* smem, int tid,
    const float* __restrict__ wt, const float* __restrict__ bt,
    const float* __restrict__ wsp, const float* __restrict__ bsp,
    const float* __restrict__ w2, const float* __restrict__ b2,
    const float* __restrict__ w3, const float* __restrict__ b3,
    const float* __restrict__ w4, const float* __restrict__ b4,
    float* __restrict__ wsf, short* __restrict__ wss) {
    if (vb == 0) {
        float* bacc = (float*)smem;
        if (tid < 32) bacc[tid] = 0.f;
        __syncthreads();
        for (int p = tid; p < 625; p += 256) {      // combined bias reduction
            int o = p / 25, i = p - o * 25;
            float rs = 0.f;
            for (int c = 0; c < 22; ++c) rs += wsp[(o * 25 + i) * 22 + c];
            atomicAdd(&bacc[o], bt[i] * rs);
        }
        __syncthreads();
        for (int idx = tid; idx < 448; idx += 256) {
            float v;
            if (idx < 32)        v = (idx < 25) ? bsp[idx] + bacc[idx] : 0.f;
            else if (idx < 96)  { int o = idx - 32;  v = (o < 50)  ? b2[o] : 0.f; }
            else if (idx < 224) { int o = idx - 96;  v = (o < 100) ? b3[o] : 0.f; }
            else                { int o = idx - 224; v = (o < 200) ? b4[o] : 0.f; }
            wsf[idx] = v;
        }
        __syncthreads();
        return;
    }
    int j = (vb - 1) * 256 + tid;
    if (j < 10240) {                           // wk12 combined: OPAD=32, IB=1
        int g = j >> 9, s = j & 511;
        int k = g >> 1, ot = g & 1;
        int lane = s >> 3, e = s & 7;
        int o = ot * 16 + (lane & 15), i = (lane >> 4) * 8 + e;
        float v = 0.f;
        if (o < 25 && i < 22)
            for (int q = 0; q < 25; ++q) v += wt[q * 10 + k] * wsp[(o * 25 + q) * 22 + i];
        wss[WK12 + j] = f2bf(v);
        return;
    }
    j -= 10240;
    if (j < 20480) {                           // wk3: OPAD=64, IB=1 (4 blk/k)
        int g = j >> 9, s = j & 511;
        int k = g >> 2, ot = g & 3;
        int lane = s >> 3, e = s & 7;
        int o = ot * 16 + (lane & 15), i = (lane >> 4) * 8 + e;
        float v = (o < 50 && i < 25) ? w2[(o * 25 + i) * 10 + k] : 0.f;
        wss[WK3 + j] = f2bf(v);
        return;
    }
    j -= 20480;
    if (j < 81920) {                           // wk4: OPAD=128, IB=2 (16 blk/k)
        int g = j >> 9, s = j & 511;
        int k = g >> 4, rem = g & 15, ib = rem >> 3, ot = rem & 7;
        int lane = s >> 3, e = s & 7;
        int o = ot * 16 + (lane & 15), i = ib * 32 + (lane >> 4) * 8 + e;
        float v = (o < 100 && i < 50) ? w3[(o * 50 + i) * 10 + k] : 0.f;
        wss[WK4 + j] = f2bf(v);
        return;
    }
    j -= 81920;
    if (j < 286720) {                          // wk5: OPAD=224, IB=4 (56 blk/k)
        int g = j >> 9, s = j & 511;
        int k = g / 56, rem = g % 56, ib = rem / 14, ot = rem % 14;
        int lane = s >> 3, e = s & 7;
        int o = ot * 16 + (lane & 15), i = ib * 32 + (lane >> 4) * 8 + e;
        float v = (o < 200 && i < 100) ? w4[(o * 100 + i) * 10 + k] : 0.f;
        wss[WK5 + j] = f2bf(v);
    }
}

// ---- generic MFMA conv+pool+ELU virtual block (round-4 verified body) -----
// 4 waves: wave w -> (m-tile w%WM, n-group w/WM of NT 16-wide tiles).
// vb = b + 256*(nc + NC*mc).
template<int OPAD, int IPAD, int IB, int WM, int NT, int NCHUNK, bool F32IN, bool LAST>
__device__ __forceinline__ void conv_vb(
    int vb, unsigned char* smem, int tid,
    const short* __restrict__ wk, const float* __restrict__ bias,
    const short* __restrict__ xinT, const float* __restrict__ xf32,
    short* __restrict__ outT, float* __restrict__ p4,
    int NC, int TIN, int NPtot) {
    constexpr int ROWS = NCHUNK + 9;
    constexpr int MSPAN = WM * 16;
    constexpr int XSTR = IPAD + 4;      // +4 shorts: bank-conflict-free rows
    constexpr int SSTR = MSPAN + 1;     // odd stride: conflict-free sc
    constexpr int SC_OFF = ((ROWS * XSTR * 2) + 15) & ~15;
    short* xs = (short*)smem;
    float* sc = (float*)(smem + SC_OFF);

    int b = vb % 256;
    int nc = (vb / 256) % NC;
    int mc = vb / (256 * NC);
    int t0 = nc * NCHUNK;

    // ---- stage input tile into LDS (bf16, time-major) ----
    if constexpr (F32IN) {
        const float* xb = xf32 + b * 22000;
        for (int i = tid; i < 32 * 128; i += 256) {
            int c = i >> 7, r = i & 127;
            if (r < ROWS) {
                short v = 0;
                if (c < 22) {
                    int t = t0 + r; if (t > 999) t = 999;
                    v = f2bf(xb[c * 1000 + t]);
                }
                xs[r * XSTR + c] = v;
            }
        }
    } else {
        const short* xb = xinT + (size_t)b * TIN * IPAD;
        constexpr int V = IPAD / 8;
        for (int i = tid; i < ROWS * V; i += 256) {
            int r = i / V, vv = i - r * V;
            int t = t0 + r; if (t >= TIN) t = TIN - 1;   // clamp; extras discarded
            *(short8*)(xs + r * XSTR + vv * 8) =
                *(const short8*)(xb + (size_t)t * IPAD + vv * 8);
        }
    }
    __syncthreads();

    int w = tid >> 6, lane = tid & 63, l15 = lane & 15, quad = lane >> 4;
    int mt = w % WM, ns = w / WM;
    int otg = mc * WM + mt;             // global otile index for A blocks
    int tw = ns * NT * 16;

    f32x4 acc[NT];
#pragma unroll
    for (int i = 0; i < NT; ++i) acc[i] = (f32x4){0.f, 0.f, 0.f, 0.f};

    const short* wfrag = wk + lane * 8; // lane's 16B within each 512-short block
#pragma unroll 2
    for (int k = 0; k < 10; ++k) {
#pragma unroll
        for (int ib = 0; ib < IB; ++ib) {
            short8 a = *(const short8*)(wfrag +
                (size_t)((k * IB + ib) * (OPAD / 16) + otg) * 512);
#pragma unroll
            for (int nt = 0; nt < NT; ++nt) {
                short8 bf = *(const short8*)(xs + (tw + nt * 16 + l15 + k) * XSTR +
                                             ib * 32 + quad * 8);
                acc[nt] = __builtin_amdgcn_mfma_f32_16x16x32_bf16(a, bf, acc[nt], 0, 0, 0);
            }
        }
    }

    // ---- C frags -> LDS f32 scratch, transposed: sc[col][o_local] ----
#pragma unroll
    for (int nt = 0; nt < NT; ++nt) {
        int col = tw + nt * 16 + l15;
        int rbase = mt * 16 + quad * 4;
#pragma unroll
        for (int r = 0; r < 4; ++r)
            sc[col * SSTR + rbase + r] = acc[nt][r];
    }
    __syncthreads();

    // ---- pool3 + bias + ELU + store (bf16 transposed, or f32 feats) ----
    constexpr int PC = NCHUNK / 3;
    int pc0 = nc * PC;
    for (int i = tid; i < PC * MSPAN; i += 256) {
        int tp = i / MSPAN, ol = i - tp * MSPAN;
        if (pc0 + tp < NPtot) {
            float s0 = sc[(tp * 3 + 0) * SSTR + ol];
            float s1 = sc[(tp * 3 + 1) * SSTR + ol];
            float s2 = sc[(tp * 3 + 2) * SSTR + ol];
            float m = fmaxf(fmaxf(s0, s1), s2) + bias[mc * MSPAN + ol];
            float e = m > 0.f ? m : __expf(m) - 1.f;
            if constexpr (LAST) {
                int o = mc * MSPAN + ol;
                if (o < 200) p4[(size_t)b * 1400 + o * 7 + (pc0 + tp)] = e;
            } else {
                outT[(size_t)b * NPtot * OPAD + (size_t)(pc0 + tp) * OPAD +
                     mc * MSPAN + ol] = f2bf(e);
            }
        }
    }
}

// ---- head virtual block (round-4 verified body) ---------------------------
__device__ __forceinline__ void head_vb(int b, int tid,
    const float* __restrict__ hW, const float* __restrict__ hB,
    const int* __restrict__ sid, const float* __restrict__ p4,
    float* __restrict__ out) {
    int wave = tid >> 6, lane = tid & 63;
    int sidb = sid[b];
    const float4* wrow = reinterpret_cast<const float4*>(hW + (sidb * 4 + wave) * 1400);
    const float4* feat = reinterpret_cast<const float4*>(p4 + b * 1400);
    float acc = 0.f;
    for (int f = lane; f < 350; f += 64) {
        float4 a = wrow[f], c = feat[f];
        acc += a.x * c.x + a.y * c.y + a.z * c.z + a.w * c.w;
    }
#pragma unroll
    for (int off = 32; off; off >>= 1) acc += __shfl_down(acc, off);
    if (lane == 0) out[b * 4 + wave] = acc + hB[sidb * 4 + wave];
}

// ---- mode (a): single cooperative kernel, grid-stride phases --------------
__global__ __launch_bounds__(256, 4) void k_all(
    const float* __restrict__ x, const int* __restrict__ sid,
    const float* __restrict__ wt, const float* __restrict__ bt,
    const float* __restrict__ wsp, const float* __restrict__ bsp,
    const float* __restrict__ w2, const float* __restrict__ b2,
    const float* __restrict__ w3, const float* __restrict__ b3,
    const float* __restrict__ w4, const float* __restrict__ b4,
    const float* __restrict__ hW, const float* __restrict__ hB,
    float* __restrict__ out, float* __restrict__ wsf, short* __restrict__ wss,
    int nblk) {
    __shared__ __align__(16) unsigned char smem[SMEM_BYTES];
    cg::grid_group grid = cg::this_grid();
    int tid = threadIdx.x;

    for (int vb = blockIdx.x; vb < 1561; vb += nblk)
        prep_vb(vb, smem, tid, wt, bt, wsp, bsp, w2, b2, w3, b3, w4, b4, wsf, wss);
    __threadfence(); grid.sync();

    for (int vb = blockIdx.x; vb < 2816; vb += nblk)   // conv12: 11 nc of 96
        conv_vb<32, 32, 1, 2, 3, 96, true, false>(vb, smem, tid,
            wss + WK12, wsf + F_BC, nullptr, x, wss + P1T, nullptr, 11, 1000, 330);
    __threadfence(); grid.sync();

    for (int vb = blockIdx.x; vb < 1792; vb += nblk)   // conv3: 7 nc of 48
        conv_vb<64, 32, 1, 4, 3, 48, false, false>(vb, smem, tid,
            wss + WK3, wsf + F_B2, wss + P1T, nullptr, wss + P2T, nullptr, 7, 330, 107);
    __threadfence(); grid.sync();

    for (int vb = blockIdx.x; vb < 1024; vb += nblk)   // conv4: 2 mc x 2 nc
        conv_vb<128, 64, 2, 4, 3, 48, false, false>(vb, smem, tid,
            wss + WK4, wsf + F_B3, wss + P2T, nullptr, wss + P3T, nullptr, 2, 107, 32);
    __threadfence(); grid.sync();

    for (int vb = blockIdx.x; vb < 1792; vb += nblk)   // conv5: 7 mc
        conv_vb<224, 128, 4, 2, 1, 32, false, true>(vb, smem, tid,
            wss + WK5, wsf + F_B4, wss + P3T, nullptr, nullptr, wsf + F_P4, 1, 32, 7);
    __threadfence(); grid.sync();

    for (int vb = blockIdx.x; vb < 256; vb += nblk)    // head
        head_vb(vb, tid, hW, hB, sid, wsf + F_P4, out);
}

// ---- mode (b): fallback multi-kernel wrappers (round-4 verified path) -----
__global__ __launch_bounds__(256) void k_prep2(
    const float* __restrict__ wt, const float* __restrict__ bt,
    const float* __restrict__ wsp, const float* __restrict__ bsp,
    const float* __restrict__ w2, const float* __restrict__ b2,
    const float* __restrict__ w3, const float* __restrict__ b3,
    const float* __restrict__ w4, const float* __restrict__ b4,
    float* __restrict__ wsf, short* __restrict__ wss) {
    __shared__ __align__(16) unsigned char smem[256];
    prep_vb(blockIdx.x, smem, threadIdx.x, wt, bt, wsp, bsp, w2, b2, w3, b3,
            w4, b4, wsf, wss);
}

template<int OPAD, int IPAD, int IB, int WM, int NT, int NCHUNK, bool F32IN, bool LAST>
__global__ __launch_bounds__(256) void k_cmfma(
    const short* __restrict__ wk, const float* __restrict__ bias,
    const short* __restrict__ xinT, const float* __restrict__ xf32,
    short* __restrict__ outT, float* __restrict__ p4,
    int NC, int TIN, int NPtot) {
    __shared__ __align__(16) unsigned char smem[SMEM_BYTES];
    conv_vb<OPAD, IPAD, IB, WM, NT, NCHUNK, F32IN, LAST>(
        blockIdx.x, smem, threadIdx.x, wk, bias, xinT, xf32, outT, p4,
        NC, TIN, NPtot);
}

__global__ __launch_bounds__(256) void k_head(const float* __restrict__ hW,
                                              const float* __restrict__ hB,
                                              const int* __restrict__ sid,
                                              const float* __restrict__ p4,
                                              float* __restrict__ out) {
    head_vb(blockIdx.x, threadIdx.x, hW, hB, sid, p4, out);
}

extern "C" void kernel_launch(void* const* d_in, const int* in_sizes, int n_in,
                              void* d_out, int out_size, void* d_ws, size_t ws_size,
                              hipStream_t stream) {
    const float* x   = (const float*)d_in[0];
    const int*   sid = (const int*)d_in[1];
    const float* wt  = (const float*)d_in[2];
    const float* bt  = (const float*)d_in[3];
    const float* wsp = (const float*)d_in[4];
    const float* bsp = (const float*)d_in[5];
    const float* w2  = (const float*)d_in[6];
    const float* b2  = (const float*)d_in[7];
    const float* w3  = (const float*)d_in[8];
    const float* b3  = (const float*)d_in[9];
    const float* w4  = (const float*)d_in[10];
    const float* b4  = (const float*)d_in[11];
    const float* hW  = (const float*)d_in[12];
    const float* hB  = (const float*)d_in[13];
    float* out = (float*)d_out;
    float* wsf = (float*)d_ws;
    short* wss = (short*)d_ws + SHORT_BASE;

    // ---- try cooperative single-launch; runtime-sized grid ----
    int maxb = 0;
    hipError_t qe = hipOccupancyMaxActiveBlocksPerMultiprocessor(
        &maxb, (const void*)k_all, 256, 0);
    hipError_t le = hipErrorUnknown;
    if (qe == hipSuccess && maxb >= 1) {
        int nblk = maxb * 256;              // 256 CUs on MI355X
        if (nblk > 1024) nblk = 1024;       // no benefit past 4 blocks/CU
        void* kargs[] = {
            (void*)&x, (void*)&sid, (void*)&wt, (void*)&bt, (void*)&wsp,
            (void*)&bsp, (void*)&w2, (void*)&b2, (void*)&w3, (void*)&b3,
            (void*)&w4, (void*)&b4, (void*)&hW, (void*)&hB,
            (void*)&out, (void*)&wsf, (void*)&wss, (void*)&nblk
        };
        le = hipLaunchCooperativeKernel((const void*)k_all, dim3(nblk),
                                        dim3(256), kargs, 0, stream);
    }
    if (le == hipSuccess) return;
    (void)hipGetLastError();                // clear failed-coop error state

    // ---- fallback: verified multi-kernel path (round-4, 148.7us) ----
    k_prep2<<<1561, 256, 0, stream>>>(wt, bt, wsp, bsp, w2, b2, w3, b3, w4, b4,
                                      wsf, wss);
    k_cmfma<32, 32, 1, 2, 3, 96, true, false><<<256 * 11, 256, 0, stream>>>(
        wss + WK12, wsf + F_BC, nullptr, x, wss + P1T, nullptr, 11, 1000, 330);
    k_cmfma<64, 32, 1, 4, 3, 48, false, false><<<256 * 7, 256, 0, stream>>>(
        wss + WK3, wsf + F_B2, wss + P1T, nullptr, wss + P2T, nullptr, 7, 330, 107);
    k_cmfma<128, 64, 2, 4, 3, 48, false, false><<<256 * 2 * 2, 256, 0, stream>>>(
        wss + WK4, wsf + F_B3, wss + P2T, nullptr, wss + P3T, nullptr, 2, 107, 32);
    k_cmfma<224, 128, 4, 2, 1, 32, false, true><<<256 * 7, 256, 0, stream>>>(
        wss + WK5, wsf + F_B4, wss + P3T, nullptr, nullptr, wsf + F_P4, 1, 32, 7);
    k_head<<<256, 256, 0, stream>>>(hW, hB, sid, wsf + F_P4, out);
}

// Round 7
// 228.179 us; speedup vs baseline: 4.2788x; 4.2788x over previous
//
#include <hip/hip_runtime.h>
#include <math.h>

// ---------------------------------------------------------------------------
// Deep4Net via bf16 MFMA (fp32 accum). Multi-kernel, high-occupancy.
// Round-6 lesson: cooperative grid.sync costs ~170us/sync on 8-XCD gfx950
// (device-scope L2 writeback) -> phases-in-one-kernel is unusable; the
// multi-kernel structure with per-launch boundaries is the right shape.
// This round: (a) alias xs/sc LDS (disjoint lifetimes, extra barrier) ->
// 12.5-12.7KB/block -> 8 blocks/CU via __launch_bounds__(256,8) (2x TLP);
// (b) head folded into conv5 (feats slice already in LDS; atomicAdd out,
// harness memsets out=0 pre-launch) -> 5 launches, no p4 round-trip.
//
// conv1+conv2 fused algebraically; pool(elu)=elu(pool).
//   out[o][t] += sum_i wk[k][o][i] * xT[t+k][i]
// Weights FRAGMENT-ORDERED by prep: for each (k, ib, otile) a 512-short
// block where lane l holds shorts [l*8..+7] = its exact MFMA A-fragment ->
// wave A-load = one coalesced 1KB global_load_dwordx4.
// B-frag: xT[t][i: quad*8..+7] staged in LDS (rows padded +4 shorts).
// Epilogue scratch sc transposed [col][o], odd stride MSPAN+1 (aliases xs).
//
// Workspace: float region then short(bf16) region.
#define F_BC   0         // 32   combined bias (padded)
#define F_B2   32        // 64
#define F_B3   96        // 128
#define F_B4   224       // 224
#define SHORT_BASE 717696  // short index of bf16 region
#define WK12   0         // [10][1][2][512]   (k, ib, otile, frag)
#define WK3    10240     // [10][1][4][512]
#define WK4    30720     // [10][2][8][512]
#define WK5    112640    // [10][4][14][512]
#define P1T    399360    // [256][330][32]
#define P2T    3102720   // [256][107][64]
#define P3T    4855808   // [256][32][128]
// ---------------------------------------------------------------------------

typedef __attribute__((ext_vector_type(8))) short short8;
typedef __attribute__((ext_vector_type(4))) float f32x4;

__device__ __forceinline__ short f2bf(float f) {
    union { float f; unsigned u; } v; v.f = f;
    unsigned r = v.u + 0x7FFF + ((v.u >> 16) & 1);
    return (short)(r >> 16);
}

// ---- K0: weight prep (verified round-4 body) -------------------------------
__global__ __launch_bounds__(256) void k_prep2(
    const float* __restrict__ wt, const float* __restrict__ bt,
    const float* __restrict__ wsp, const float* __restrict__ bsp,
    const float* __restrict__ w2, const float* __restrict__ b2,
    const float* __restrict__ w3, const float* __restrict__ b3,
    const float* __restrict__ w4, const float* __restrict__ b4,
    float* __restrict__ wsf, short* __restrict__ wss) {
    int tid = threadIdx.x;
    if (blockIdx.x == 0) {
        __shared__ float bacc[32];
        if (tid < 32) bacc[tid] = 0.f;
        __syncthreads();
        for (int p = tid; p < 625; p += 256) {      // combined bias reduction
            int o = p / 25, i = p - o * 25;
            float rs = 0.f;
            for (int c = 0; c < 22; ++c) rs += wsp[(o * 25 + i) * 22 + c];
            atomicAdd(&bacc[o], bt[i] * rs);
        }
        __syncthreads();
        for (int idx = tid; idx < 448; idx += 256) {
            float v;
            if (idx < 32)        v = (idx < 25) ? bsp[idx] + bacc[idx] : 0.f;
            else if (idx < 96)  { int o = idx - 32;  v = (o < 50)  ? b2[o] : 0.f; }
            else if (idx < 224) { int o = idx - 96;  v = (o < 100) ? b3[o] : 0.f; }
            else                { int o = idx - 224; v = (o < 200) ? b4[o] : 0.f; }
            wsf[idx] = v;
        }
        return;
    }
    int j = (blockIdx.x - 1) * 256 + tid;
    if (j < 10240) {                           // wk12 combined: OPAD=32, IB=1
        int g = j >> 9, s = j & 511;
        int k = g >> 1, ot = g & 1;
        int lane = s >> 3, e = s & 7;
        int o = ot * 16 + (lane & 15), i = (lane >> 4) * 8 + e;
        float v = 0.f;
        if (o < 25 && i < 22)
            for (int q = 0; q < 25; ++q) v += wt[q * 10 + k] * wsp[(o * 25 + q) * 22 + i];
        wss[WK12 + j] = f2bf(v);
        return;
    }
    j -= 10240;
    if (j < 20480) {                           // wk3: OPAD=64, IB=1 (4 blk/k)
        int g = j >> 9, s = j & 511;
        int k = g >> 2, ot = g & 3;
        int lane = s >> 3, e = s & 7;
        int o = ot * 16 + (lane & 15), i = (lane >> 4) * 8 + e;
        float v = (o < 50 && i < 25) ? w2[(o * 25 + i) * 10 + k] : 0.f;
        wss[WK3 + j] = f2bf(v);
        return;
    }
    j -= 20480;
    if (j < 81920) {                           // wk4: OPAD=128, IB=2 (16 blk/k)
        int g = j >> 9, s = j & 511;
        int k = g >> 4, rem = g & 15, ib = rem >> 3, ot = rem & 7;
        int lane = s >> 3, e = s & 7;
        int o = ot * 16 + (lane & 15), i = ib * 32 + (lane >> 4) * 8 + e;
        float v = (o < 100 && i < 50) ? w3[(o * 50 + i) * 10 + k] : 0.f;
        wss[WK4 + j] = f2bf(v);
        return;
    }
    j -= 81920;
    if (j < 286720) {                          // wk5: OPAD=224, IB=4 (56 blk/k)
        int g = j >> 9, s = j & 511;
        int k = g / 56, rem = g % 56, ib = rem / 14, ot = rem % 14;
        int lane = s >> 3, e = s & 7;
        int o = ot * 16 + (lane & 15), i = ib * 32 + (lane >> 4) * 8 + e;
        float v = (o < 200 && i < 100) ? w4[(o * 100 + i) * 10 + k] : 0.f;
        wss[WK5 + j] = f2bf(v);
    }
}

// ---- generic MFMA conv+pool+ELU layer -------------------------------------
// block = 4 waves: wave w -> (m-tile w%WM, n-group w/WM of NT 16-wide tiles)
// grid: idx = b + 256*(nc + NC*mc)
// LDS: sc ALIASES xs (xs last read = final MFMA; barrier; then sc writes).
// LAST: feats after sc; head partial-dot folded in, atomicAdd into out.
template<int OPAD, int IPAD, int IB, int WM, int NT, int NCHUNK, bool F32IN, bool LAST>
__global__ __launch_bounds__(256, 8) void k_cmfma(
    const short* __restrict__ wk, const float* __restrict__ bias,
    const short* __restrict__ xinT, const float* __restrict__ xf32,
    short* __restrict__ outT,
    const float* __restrict__ hW, const float* __restrict__ hB,
    const int* __restrict__ sid, float* __restrict__ out,
    int NC, int TIN, int NPtot) {
    constexpr int ROWS = NCHUNK + 9;
    constexpr int MSPAN = WM * 16;
    constexpr int XSTR = IPAD + 4;      // +4 shorts: bank-conflict-free rows
    constexpr int SSTR = MSPAN + 1;     // odd stride: conflict-free sc
    constexpr int XS_B = ROWS * XSTR * 2;
    constexpr int SC_B = NCHUNK * SSTR * 4;
    constexpr int FE_B = LAST ? MSPAN * 7 * 4 : 0;
    constexpr int SMEMB = ((SC_B + FE_B) > XS_B ? (SC_B + FE_B) : XS_B);
    __shared__ __align__(16) unsigned char smem[SMEMB];
    short* xs = (short*)smem;                    // staged input (phase A)
    float* sc = (float*)smem;                    // C-frag scratch (phase B)
    float* feats = (float*)(smem + SC_B);        // LAST only

    int idx = blockIdx.x;
    int b = idx % 256;
    int nc = (idx / 256) % NC;
    int mc = idx / (256 * NC);
    int t0 = nc * NCHUNK;
    int tid = threadIdx.x;

    // ---- stage input tile into LDS (bf16, time-major) ----
    if constexpr (F32IN) {
        const float* xb = xf32 + b * 22000;
        for (int i = tid; i < 32 * 128; i += 256) {
            int c = i >> 7, r = i & 127;
            if (r < ROWS) {
                short v = 0;
                if (c < 22) {
                    int t = t0 + r; if (t > 999) t = 999;
                    v = f2bf(xb[c * 1000 + t]);
                }
                xs[r * XSTR + c] = v;
            }
        }
    } else {
        const short* xb = xinT + (size_t)b * TIN * IPAD;
        constexpr int V = IPAD / 8;
        for (int i = tid; i < ROWS * V; i += 256) {
            int r = i / V, vv = i - r * V;
            int t = t0 + r; if (t >= TIN) t = TIN - 1;   // clamp; extras discarded
            *(short8*)(xs + r * XSTR + vv * 8) =
                *(const short8*)(xb + (size_t)t * IPAD + vv * 8);
        }
    }
    __syncthreads();

    int w = tid >> 6, lane = tid & 63, l15 = lane & 15, quad = lane >> 4;
    int mt = w % WM, ns = w / WM;
    int otg = mc * WM + mt;             // global otile index for A blocks
    int tw = ns * NT * 16;

    f32x4 acc[NT];
#pragma unroll
    for (int i = 0; i < NT; ++i) acc[i] = (f32x4){0.f, 0.f, 0.f, 0.f};

    const short* wfrag = wk + lane * 8; // lane's 16B within each 512-short block
#pragma unroll 2
    for (int k = 0; k < 10; ++k) {
#pragma unroll
        for (int ib = 0; ib < IB; ++ib) {
            short8 a = *(const short8*)(wfrag +
                (size_t)((k * IB + ib) * (OPAD / 16) + otg) * 512);
#pragma unroll
            for (int nt = 0; nt < NT; ++nt) {
                short8 bf = *(const short8*)(xs + (tw + nt * 16 + l15 + k) * XSTR +
                                             ib * 32 + quad * 8);
                acc[nt] = __builtin_amdgcn_mfma_f32_16x16x32_bf16(a, bf, acc[nt], 0, 0, 0);
            }
        }
    }
    __syncthreads();   // all xs reads done -> sc may alias xs

    // ---- C frags -> LDS f32 scratch, transposed: sc[col][o_local] ----
#pragma unroll
    for (int nt = 0; nt < NT; ++nt) {
        int col = tw + nt * 16 + l15;
        int rbase = mt * 16 + quad * 4;
#pragma unroll
        for (int r = 0; r < 4; ++r)
            sc[col * SSTR + rbase + r] = acc[nt][r];
    }
    __syncthreads();

    // ---- pool3 + bias + ELU + store (bf16 transposed, or LDS feats) ----
    constexpr int PC = NCHUNK / 3;
    int pc0 = nc * PC;
    for (int i = tid; i < PC * MSPAN; i += 256) {
        int tp = i / MSPAN, ol = i - tp * MSPAN;
        if (pc0 + tp < NPtot) {
            float s0 = sc[(tp * 3 + 0) * SSTR + ol];
            float s1 = sc[(tp * 3 + 1) * SSTR + ol];
            float s2 = sc[(tp * 3 + 2) * SSTR + ol];
            float m = fmaxf(fmaxf(s0, s1), s2) + bias[mc * MSPAN + ol];
            float e = m > 0.f ? m : __expf(m) - 1.f;
            if constexpr (LAST) {
                int o = mc * MSPAN + ol;
                if (o < 200) feats[ol * 7 + (pc0 + tp)] = e;
            } else {
                outT[(size_t)b * NPtot * OPAD + (size_t)(pc0 + tp) * OPAD +
                     mc * MSPAN + ol] = f2bf(e);
            }
        }
    }

    if constexpr (LAST) {
        // ---- folded head: wave w -> output w; this block's feats slice ----
        __syncthreads();
        int nvo = 200 - mc * MSPAN; if (nvo > MSPAN) nvo = MSPAN;
        int nvalid = nvo * 7;                    // 224, or 56 at mc==6
        int s = sid[b];
        const float* wrow = hW + (size_t)(s * 4 + w) * 1400 + mc * MSPAN * 7;
        float hacc = 0.f;
        for (int f = lane; f < nvalid; f += 64) hacc += wrow[f] * feats[f];
#pragma unroll
        for (int off = 32; off; off >>= 1) hacc += __shfl_down(hacc, off);
        if (lane == 0) {
            if (mc == 0) hacc += hB[s * 4 + w];
            atomicAdd(&out[b * 4 + w], hacc);   // out memset-0 by harness
        }
    }
}

extern "C" void kernel_launch(void* const* d_in, const int* in_sizes, int n_in,
                              void* d_out, int out_size, void* d_ws, size_t ws_size,
                              hipStream_t stream) {
    const float* x   = (const float*)d_in[0];
    const int*   sid = (const int*)d_in[1];
    const float* wt  = (const float*)d_in[2];
    const float* bt  = (const float*)d_in[3];
    const float* wsp = (const float*)d_in[4];
    const float* bsp = (const float*)d_in[5];
    const float* w2  = (const float*)d_in[6];
    const float* b2  = (const float*)d_in[7];
    const float* w3  = (const float*)d_in[8];
    const float* b3  = (const float*)d_in[9];
    const float* w4  = (const float*)d_in[10];
    const float* b4  = (const float*)d_in[11];
    const float* hW  = (const float*)d_in[12];
    const float* hB  = (const float*)d_in[13];
    float* out = (float*)d_out;
    float* wsf = (float*)d_ws;
    short* wss = (short*)d_ws + SHORT_BASE;

    // prep: block 0 = biases; blocks 1..1560 = 399360 weight elements
    k_prep2<<<1561, 256, 0, stream>>>(wt, bt, wsp, bsp, w2, b2, w3, b3, w4, b4,
                                      wsf, wss);
    // conv12: M=32(25), 330 pooled; 11 n-chunks of 96  (12.7KB LDS)
    k_cmfma<32, 32, 1, 2, 3, 96, true, false><<<256 * 11, 256, 0, stream>>>(
        wss + WK12, wsf + F_BC, nullptr, x, wss + P1T,
        nullptr, nullptr, nullptr, nullptr, 11, 1000, 330);
    // conv3: M=64(50), 107 pooled; 7 n-chunks of 48  (12.5KB LDS)
    k_cmfma<64, 32, 1, 4, 3, 48, false, false><<<256 * 7, 256, 0, stream>>>(
        wss + WK3, wsf + F_B2, wss + P1T, nullptr, wss + P2T,
        nullptr, nullptr, nullptr, nullptr, 7, 330, 107);
    // conv4: M=128(100) in 2 m-chunks, 32 pooled; 2 n-chunks  (12.5KB LDS)
    k_cmfma<128, 64, 2, 4, 3, 48, false, false><<<256 * 2 * 2, 256, 0, stream>>>(
        wss + WK4, wsf + F_B3, wss + P2T, nullptr, wss + P3T,
        nullptr, nullptr, nullptr, nullptr, 2, 107, 32);
    // conv5+head: M=224(200) in 7 m-chunks, 7 pooled  (29.7KB LDS)
    k_cmfma<224, 128, 4, 2, 1, 32, false, true><<<256 * 7, 256, 0, stream>>>(
        wss + WK5, wsf + F_B4, wss + P3T, nullptr, nullptr,
        hW, hB, sid, out, 1, 32, 7);
}